// Round 4
// baseline (342.476 us; speedup 1.0000x reference)
//
#include <hip/hip_runtime.h>

#define HID 128
#define F_IN 11
#define FP 16
#define N_ACT 6
#define EPB 2048   // edges per block for pack/bucket kernels (must match!)

typedef __bf16 bf16;
typedef __bf16 v8bf __attribute__((ext_vector_type(8)));
typedef float f32x4 __attribute__((ext_vector_type(4)));

__device__ inline float lo16(unsigned u) { return __uint_as_float(u << 16); }
__device__ inline float hi16(unsigned u) { return __uint_as_float(u & 0xffff0000u); }

// ---------------- CSR build (two-level counting sort; requires N < 65536) ----------------

// pack edges to (dst<<16)|src + LDS-privatized bucket histogram (bucket = dst>>8)
__global__ __launch_bounds__(256) void k_pack_hist(const int* __restrict__ esrc,
                                                   const int* __restrict__ edst,
                                                   unsigned* __restrict__ ep,
                                                   int* __restrict__ bhist,
                                                   int E, int nbkt) {
  __shared__ int hist[256];
  int t = threadIdx.x;
  hist[t] = 0;
  __syncthreads();
  int start = blockIdx.x * EPB;
  int end = min(E, start + EPB);
  for (int e = start + t; e < end; e += 256) {
    int s = esrc[e], d = edst[e];
    ep[e] = ((unsigned)d << 16) | (unsigned)s;
    atomicAdd(&hist[d >> 8], 1);
  }
  __syncthreads();
  int sub = blockIdx.x & 7;
  if (t < nbkt && hist[t]) atomicAdd(&bhist[t * 8 + sub], hist[t]);
}

// scan nbkt*8 sub-bucket counts -> bbase/bcur; bucketbase[b] = bbase[b*8]
__global__ __launch_bounds__(256) void k_bscan(const int* __restrict__ bhist,
                                               int* __restrict__ bcur,
                                               int* __restrict__ bucketbase,
                                               int nbkt, int E) {
  __shared__ int vals[2048];
  __shared__ int tsum[256];
  int t = threadIdx.x;
  int nsub = nbkt * 8;
  int loc[8];
  int s = 0;
#pragma unroll
  for (int i = 0; i < 8; ++i) {
    int idx = t * 8 + i;
    int v = (idx < nsub) ? bhist[idx] : 0;
    loc[i] = s;
    s += v;
  }
  tsum[t] = s;
  __syncthreads();
  for (int off = 1; off < 256; off <<= 1) {
    int x = (t >= off) ? tsum[t - off] : 0;
    __syncthreads();
    tsum[t] += x;
    __syncthreads();
  }
  int tbase = tsum[t] - s;  // exclusive
#pragma unroll
  for (int i = 0; i < 8; ++i) {
    int idx = t * 8 + i;
    if (idx < nsub) {
      int v = tbase + loc[i];
      vals[idx] = v;
      bcur[idx] = v;
    }
  }
  __syncthreads();
  if (t < nbkt) bucketbase[t] = vals[t * 8];
  if (t == 0) bucketbase[nbkt] = E;
}

// scatter packed edges into bucket regions; sub-bucket by blockIdx&7 (~XCD-local)
__global__ __launch_bounds__(256) void k_bucket(const unsigned* __restrict__ ep,
                                                int* __restrict__ bcur,
                                                unsigned* __restrict__ ebuf, int E) {
  int start = blockIdx.x * EPB;
  int end = min(E, start + EPB);
  int sub = blockIdx.x & 7, t = threadIdx.x;
  for (int e = start + t; e < end; e += 256) {
    unsigned u = ep[e];
    int b = (int)(u >> 24);  // (dst>>8) = bucket
    int p = atomicAdd(&bcur[b * 8 + sub], 1);
    ebuf[p] = u;
  }
}

// one workgroup per bucket: local hist + scan + fill. Writes rowptr, dinv, cs(ushort).
__global__ __launch_bounds__(256) void k_local(const unsigned* __restrict__ ebuf,
                                               const int* __restrict__ bucketbase,
                                               int* __restrict__ rowptr,
                                               float* __restrict__ dinv,
                                               unsigned short* __restrict__ cs,
                                               int n) {
  __shared__ int hist[256], lofs[256], cur[256];
  int b = blockIdx.x, t = threadIdx.x;
  int rb = bucketbase[b], re = bucketbase[b + 1];
  int nbase = b << 8;
  hist[t] = 0;
  __syncthreads();
  for (int e = rb + t; e < re; e += 256) {
    int dl = (int)(ebuf[e] >> 16) - nbase;
    atomicAdd(&hist[dl], 1);
  }
  __syncthreads();
  int h = hist[t];
  lofs[t] = h;
  __syncthreads();
  for (int off = 1; off < 256; off <<= 1) {
    int x = (t >= off) ? lofs[t - off] : 0;
    __syncthreads();
    lofs[t] += x;
    __syncthreads();
  }
  int excl = lofs[t] - h;
  cur[t] = rb + excl;
  int g = nbase + t;
  if (g <= n) rowptr[g] = rb + excl;   // g==n lands here for the last bucket
  if (g < n) dinv[g] = rsqrtf((float)h + 1.0f);
  __syncthreads();
  for (int e = rb + t; e < re; e += 256) {
    unsigned u = ebuf[e];
    int dl = (int)(u >> 16) - nbase;
    int p = atomicAdd(&cur[dl], 1);
    cs[p] = (unsigned short)(u & 0xffffu);
  }
}

// ---------------- feature prep ----------------

// xs = x * dinv (bf16, padded to 16 cols)
__global__ __launch_bounds__(256) void k_pad(const float* __restrict__ x,
                                             const float* __restrict__ dinv,
                                             bf16* __restrict__ xs, int n) {
  int i = blockIdx.x * 256 + threadIdx.x;
  if (i >= n * FP) return;
  int node = i >> 4, c = i & 15;
  float v = (c < F_IN) ? x[(size_t)node * F_IN + c] * dinv[node] : 0.f;
  xs[i] = (bf16)v;
}

// WT[n][k] = bf16(W[k][n]) for both 128x128 layer weights
__global__ __launch_bounds__(256) void k_prepw2(const float* __restrict__ W2,
                                                const float* __restrict__ W3,
                                                bf16* __restrict__ WT2,
                                                bf16* __restrict__ WT3) {
  int i = blockIdx.x * 256 + threadIdx.x;  // 16384
  int nn = i >> 7, k = i & 127;
  WT2[i] = (bf16)W2[k * 128 + nn];
  WT3[i] = (bf16)W3[k * 128 + nn];
}

// ---------------- gathers ----------------

// A1[d] = dinv[d] * (xs[d] + sum xs[src])   [n][16] bf16
__global__ __launch_bounds__(256) void k_gather16(const bf16* __restrict__ xs,
                                                  const float* __restrict__ dinv,
                                                  const int* __restrict__ rowptr,
                                                  const unsigned short* __restrict__ cs,
                                                  bf16* __restrict__ A, int n) {
  int t = threadIdx.x;
  int node = blockIdx.x * 16 + (t >> 4);
  int c = t & 15;
  if (node >= n) return;
  float acc = (float)xs[(size_t)node * FP + c];
  int j = rowptr[node], jend = rowptr[node + 1];
  for (; j + 1 < jend; j += 2) {
    int s0 = cs[j], s1 = cs[j + 1];
    acc += (float)xs[(size_t)s0 * FP + c];
    acc += (float)xs[(size_t)s1 * FP + c];
  }
  if (j < jend) acc += (float)xs[(size_t)cs[j] * FP + c];
  A[(size_t)node * FP + c] = (bf16)(acc * dinv[node]);
}

// A[d] = dinv[d] * (hs[d] + sum hs[src])    [n][128] bf16; one wave per node
__global__ __launch_bounds__(256) void k_gather128(const bf16* __restrict__ hs,
                                                   const float* __restrict__ dinv,
                                                   const int* __restrict__ rowptr,
                                                   const unsigned short* __restrict__ cs,
                                                   bf16* __restrict__ A, int n) {
  int t = threadIdx.x;
  int node = blockIdx.x * 4 + (t >> 6);
  int l = t & 63;
  if (node >= n) return;
  const unsigned* h2 = (const unsigned*)hs;
  unsigned sv = h2[(size_t)node * 64 + l];
  float ax = lo16(sv), ay = hi16(sv);
  int j = rowptr[node], jend = rowptr[node + 1];
  for (; j + 3 < jend; j += 4) {
    int s0 = cs[j], s1 = cs[j + 1], s2 = cs[j + 2], s3 = cs[j + 3];
    unsigned v0 = h2[(size_t)s0 * 64 + l];
    unsigned v1 = h2[(size_t)s1 * 64 + l];
    unsigned v2 = h2[(size_t)s2 * 64 + l];
    unsigned v3 = h2[(size_t)s3 * 64 + l];
    ax += lo16(v0); ay += hi16(v0);
    ax += lo16(v1); ay += hi16(v1);
    ax += lo16(v2); ay += hi16(v2);
    ax += lo16(v3); ay += hi16(v3);
  }
  for (; j < jend; ++j) {
    unsigned v0 = h2[(size_t)cs[j] * 64 + l];
    ax += lo16(v0); ay += hi16(v0);
  }
  float dd = dinv[node];
  bf16* ap = A + (size_t)node * 128 + l * 2;
  ap[0] = (bf16)(ax * dd);
  ap[1] = (bf16)(ay * dd);
}

// ---------------- GEMMs ----------------

// A1[n,16(11 used)] @ W1[11,128] -> relu(+b)*dinv -> hs [n][128] bf16
__global__ __launch_bounds__(256) void k_gemm_in(const bf16* __restrict__ A1,
                                                 const float* __restrict__ W1,
                                                 const float* __restrict__ b1,
                                                 const float* __restrict__ dinv,
                                                 bf16* __restrict__ hs, int n) {
  __shared__ float Ws[F_IN * HID];
  int tid = threadIdx.x;
  for (int i = tid; i < F_IN * HID; i += 256) Ws[i] = W1[i];
  __syncthreads();
  int node = blockIdx.x * 16 + (tid >> 4);
  int cg = tid & 15;
  if (node >= n) return;
  float xr[F_IN];
#pragma unroll
  for (int k = 0; k < F_IN; ++k) xr[k] = (float)A1[(size_t)node * FP + k];
  float acc[8];
#pragma unroll
  for (int j = 0; j < 8; ++j) acc[j] = 0.f;
#pragma unroll
  for (int k = 0; k < F_IN; ++k) {
    const float* wr = &Ws[k * HID + cg * 8];
#pragma unroll
    for (int j = 0; j < 8; ++j) acc[j] = fmaf(xr[k], wr[j], acc[j]);
  }
  float dd = dinv[node];
  bf16* op = hs + (size_t)node * HID + cg * 8;
#pragma unroll
  for (int j = 0; j < 8; ++j)
    op[j] = (bf16)(fmaxf(acc[j] + b1[cg * 8 + j], 0.f) * dd);
}

// A[n,128](bf16) @ WT^T (bf16) -> relu(+b)*dinv -> H bf16. 64 nodes/block, MFMA 16x16x32.
__global__ __launch_bounds__(256) void k_gemm_mfma(const bf16* __restrict__ A,
                                                   const bf16* __restrict__ WT,
                                                   const float* __restrict__ b,
                                                   const float* __restrict__ dinv,
                                                   bf16* __restrict__ H, int n) {
  __shared__ bf16 Asm[64 * 128];
  __shared__ bf16 Wsm[128 * 128];
  int tid = threadIdx.x;
  int n0 = blockIdx.x * 64;
  {
    float4* As4 = (float4*)Asm;
#pragma unroll
    for (int it = 0; it < 4; ++it) {
      int i = tid + it * 256;
      int row = i >> 4, kc = i & 15;
      float4 v = make_float4(0.f, 0.f, 0.f, 0.f);
      if (n0 + row < n) v = ((const float4*)(A + (size_t)(n0 + row) * 128))[kc];
      As4[row * 16 + (kc ^ (row & 7))] = v;
    }
    const float4* Wg = (const float4*)WT;
    float4* Ws4 = (float4*)Wsm;
#pragma unroll
    for (int it = 0; it < 8; ++it) {
      int i = tid + it * 256;
      int row = i >> 4, kc = i & 15;
      Ws4[row * 16 + (kc ^ (row & 7))] = Wg[i];
    }
  }
  __syncthreads();
  int lane = tid & 63, wave = tid >> 6;
  int l15 = lane & 15, g = lane >> 4;
  f32x4 acc[8];
#pragma unroll
  for (int f = 0; f < 8; ++f) acc[f] = (f32x4){0.f, 0.f, 0.f, 0.f};
  int arow = wave * 16 + l15;
  const float4* As4 = (const float4*)Asm;
  const float4* Ws4 = (const float4*)Wsm;
#pragma unroll
  for (int kk = 0; kk < 4; ++kk) {
    int kc = kk * 4 + g;
    v8bf a = *(const v8bf*)&As4[arow * 16 + (kc ^ (arow & 7))];
#pragma unroll
    for (int f = 0; f < 8; ++f) {
      int nrow = f * 16 + l15;
      v8bf bf = *(const v8bf*)&Ws4[nrow * 16 + (kc ^ (nrow & 7))];
      acc[f] = __builtin_amdgcn_mfma_f32_16x16x32_bf16(a, bf, acc[f], 0, 0, 0);
    }
  }
  int nodebase = n0 + wave * 16 + g * 4;
  float dv[4];
#pragma unroll
  for (int j = 0; j < 4; ++j)
    dv[j] = (nodebase + j < n) ? dinv[nodebase + j] : 1.f;
#pragma unroll
  for (int f = 0; f < 8; ++f) {
    float bias = b[f * 16 + l15];
#pragma unroll
    for (int j = 0; j < 4; ++j) {
      int node = nodebase + j;
      if (node < n) {
        float v = fmaxf(acc[f][j] + bias, 0.f) * dv[j];
        H[(size_t)node * 128 + f * 16 + l15] = (bf16)v;
      }
    }
  }
}

// Layer 3: same GEMM but no H write; fused column-sum into gsum (for mean pool).
__global__ __launch_bounds__(256) void k_gemm_mfma3(const bf16* __restrict__ A,
                                                    const bf16* __restrict__ WT,
                                                    const float* __restrict__ b,
                                                    float* __restrict__ gsum, int n) {
  __shared__ bf16 Asm[64 * 128];
  __shared__ bf16 Wsm[128 * 128];
  __shared__ float colacc[128];
  int tid = threadIdx.x;
  int n0 = blockIdx.x * 64;
  if (tid < 128) colacc[tid] = 0.f;
  {
    float4* As4 = (float4*)Asm;
#pragma unroll
    for (int it = 0; it < 4; ++it) {
      int i = tid + it * 256;
      int row = i >> 4, kc = i & 15;
      float4 v = make_float4(0.f, 0.f, 0.f, 0.f);
      if (n0 + row < n) v = ((const float4*)(A + (size_t)(n0 + row) * 128))[kc];
      As4[row * 16 + (kc ^ (row & 7))] = v;
    }
    const float4* Wg = (const float4*)WT;
    float4* Ws4 = (float4*)Wsm;
#pragma unroll
    for (int it = 0; it < 8; ++it) {
      int i = tid + it * 256;
      int row = i >> 4, kc = i & 15;
      Ws4[row * 16 + (kc ^ (row & 7))] = Wg[i];
    }
  }
  __syncthreads();
  int lane = tid & 63, wave = tid >> 6;
  int l15 = lane & 15, g = lane >> 4;
  f32x4 acc[8];
#pragma unroll
  for (int f = 0; f < 8; ++f) acc[f] = (f32x4){0.f, 0.f, 0.f, 0.f};
  int arow = wave * 16 + l15;
  const float4* As4 = (const float4*)Asm;
  const float4* Ws4 = (const float4*)Wsm;
#pragma unroll
  for (int kk = 0; kk < 4; ++kk) {
    int kc = kk * 4 + g;
    v8bf a = *(const v8bf*)&As4[arow * 16 + (kc ^ (arow & 7))];
#pragma unroll
    for (int f = 0; f < 8; ++f) {
      int nrow = f * 16 + l15;
      v8bf bf = *(const v8bf*)&Ws4[nrow * 16 + (kc ^ (nrow & 7))];
      acc[f] = __builtin_amdgcn_mfma_f32_16x16x32_bf16(a, bf, acc[f], 0, 0, 0);
    }
  }
  int nodebase = n0 + wave * 16 + g * 4;
#pragma unroll
  for (int f = 0; f < 8; ++f) {
    float bias = b[f * 16 + l15];
    float sf = 0.f;
#pragma unroll
    for (int j = 0; j < 4; ++j) {
      int node = nodebase + j;
      if (node < n) sf += fmaxf(acc[f][j] + bias, 0.f);
    }
    atomicAdd(&colacc[f * 16 + l15], sf);
  }
  __syncthreads();
  if (tid < 128) atomicAdd(&gsum[tid], colacc[tid]);
}

// ---------------- head ----------------

__global__ __launch_bounds__(128) void k_head(const float* __restrict__ gsum,
    const float* __restrict__ Wv1, const float* __restrict__ bv1,
    const float* __restrict__ Wv2, const float* __restrict__ bv2,
    const float* __restrict__ Wa1, const float* __restrict__ ba1,
    const float* __restrict__ Wa2, const float* __restrict__ ba2,
    float* __restrict__ out, int n) {
  __shared__ float gs[HID], ha[HID], red[2], advs[N_ACT], vsh;
  int t = threadIdx.x;
  gs[t] = gsum[t] * (1.0f / (float)n);
  __syncthreads();
  float av = bv1[t], aa = ba1[t];
  for (int k = 0; k < HID; ++k) {
    float gk = gs[k];
    av = fmaf(gk, Wv1[k * HID + t], av);
    aa = fmaf(gk, Wa1[k * HID + t], aa);
  }
  float hv = fmaxf(av, 0.f);
  ha[t] = fmaxf(aa, 0.f);
  float pv = hv * Wv2[t];
#pragma unroll
  for (int o = 32; o > 0; o >>= 1) pv += __shfl_down(pv, o);
  if ((t & 63) == 0) red[t >> 6] = pv;
  __syncthreads();
  if (t == 0) vsh = red[0] + red[1] + bv2[0];
  if (t < N_ACT) {
    float adv = ba2[t];
    for (int j = 0; j < HID; ++j) adv = fmaf(ha[j], Wa2[j * N_ACT + t], adv);
    advs[t] = adv;
  }
  __syncthreads();
  if (t < N_ACT) {
    float m = 0.f;
#pragma unroll
    for (int a = 0; a < N_ACT; ++a) m += advs[a];
    m *= (1.0f / N_ACT);
    out[t] = vsh + advs[t] - m;
  }
}

// ---------------- launch ----------------

extern "C" void kernel_launch(void* const* d_in, const int* in_sizes, int n_in,
                              void* d_out, int out_size, void* d_ws, size_t ws_size,
                              hipStream_t stream) {
  const float* x   = (const float*)d_in[0];
  const int*   ei  = (const int*)d_in[1];
  const float* W1  = (const float*)d_in[2];
  const float* b1  = (const float*)d_in[3];
  const float* W2  = (const float*)d_in[4];
  const float* b2  = (const float*)d_in[5];
  const float* W3  = (const float*)d_in[6];
  const float* b3  = (const float*)d_in[7];
  const float* Wv1 = (const float*)d_in[8];
  const float* bv1 = (const float*)d_in[9];
  const float* Wv2 = (const float*)d_in[10];
  const float* bv2 = (const float*)d_in[11];
  const float* Wa1 = (const float*)d_in[12];
  const float* ba1 = (const float*)d_in[13];
  const float* Wa2 = (const float*)d_in[14];
  const float* ba2 = (const float*)d_in[15];
  float* out = (float*)d_out;

  const int N = in_sizes[0] / F_IN;   // 50000 (< 65536 required for u16 packing)
  const int E = in_sizes[1] / 2;      // 800000
  const int* esrc = ei;
  const int* edst = ei + E;
  const int nbkt = (N + 255) >> 8;    // 196
  const int gE = (E + EPB - 1) / EPB; // pack/bucket grid (identical chunking!)

  char* p = (char*)d_ws;
  auto alloc = [&](size_t bytes) {
    void* r = (void*)p;
    p += (bytes + 1023) & ~(size_t)1023;
    return r;
  };
  unsigned* ep     = (unsigned*)alloc((size_t)E * 4);
  unsigned* ebuf   = (unsigned*)alloc((size_t)E * 4);
  int*   bhist     = (int*)alloc((size_t)nbkt * 8 * 4);
  int*   bcur      = (int*)alloc((size_t)nbkt * 8 * 4);
  int*   bktbase   = (int*)alloc((size_t)(nbkt + 1) * 4);
  int*   rowptr    = (int*)alloc((size_t)(N + 1) * 4);
  float* dinv      = (float*)alloc((size_t)N * 4);
  unsigned short* cs = (unsigned short*)alloc((size_t)E * 2);
  bf16*  xs        = (bf16*)alloc((size_t)N * FP * 2);
  bf16*  A1        = (bf16*)alloc((size_t)N * FP * 2);
  bf16*  WT2       = (bf16*)alloc(128 * 128 * 2);
  bf16*  WT3       = (bf16*)alloc(128 * 128 * 2);
  bf16*  HB        = (bf16*)alloc((size_t)N * HID * 2);
  bf16*  AB        = (bf16*)alloc((size_t)N * HID * 2);
  float* gsum      = (float*)alloc(HID * 4);

  hipMemsetAsync(bhist, 0, (size_t)nbkt * 8 * 4, stream);
  hipMemsetAsync(gsum, 0, HID * 4, stream);

  // CSR build
  k_pack_hist<<<gE, 256, 0, stream>>>(esrc, edst, ep, bhist, E, nbkt);
  k_bscan<<<1, 256, 0, stream>>>(bhist, bcur, bktbase, nbkt, E);
  k_bucket<<<gE, 256, 0, stream>>>(ep, bcur, ebuf, E);
  k_local<<<nbkt, 256, 0, stream>>>(ebuf, bktbase, rowptr, dinv, cs, N);

  // feature prep
  k_pad<<<(N * FP + 255) / 256, 256, 0, stream>>>(x, dinv, xs, N);
  k_prepw2<<<64, 256, 0, stream>>>(W2, W3, WT2, WT3);

  // layer 1
  k_gather16<<<(N + 15) / 16, 256, 0, stream>>>(xs, dinv, rowptr, cs, A1, N);
  k_gemm_in<<<(N + 15) / 16, 256, 0, stream>>>(A1, W1, b1, dinv, HB, N);

  // layer 2
  k_gather128<<<(N + 3) / 4, 256, 0, stream>>>(HB, dinv, rowptr, cs, AB, N);
  k_gemm_mfma<<<(N + 63) / 64, 256, 0, stream>>>(AB, WT2, b2, dinv, HB, N);

  // layer 3 (GEMM + fused column-sum; no H write)
  k_gather128<<<(N + 3) / 4, 256, 0, stream>>>(HB, dinv, rowptr, cs, AB, N);
  k_gemm_mfma3<<<(N + 63) / 64, 256, 0, stream>>>(AB, WT3, b3, gsum, N);

  // head
  k_head<<<1, 128, 0, stream>>>(gsum, Wv1, bv1, Wv2, bv2, Wa1, ba1, Wa2, ba2, out, N);
}

// Round 5
// 211.745 us; speedup vs baseline: 1.6174x; 1.6174x over previous
//
#include <hip/hip_runtime.h>

#define HID 128
#define F_IN 11
#define FP 16
#define N_ACT 6
#define EPB 2048   // edges per block for hist/part kernels (= 8 * 256)

typedef __bf16 bf16;
typedef __bf16 v8bf __attribute__((ext_vector_type(8)));
typedef float f32x4 __attribute__((ext_vector_type(4)));

__device__ inline float lo16(unsigned u) { return __uint_as_float(u << 16); }
__device__ inline float hi16(unsigned u) { return __uint_as_float(u & 0xffff0000u); }

// ---------------- CSR build (two-level counting sort; requires N < 65536) ----------------

// global bucket histogram (bucket = dst>>8), LDS-privatized: 196 atomics/block
__global__ __launch_bounds__(256) void k_hist(const int* __restrict__ edst,
                                              int* __restrict__ bhist, int E, int nbkt) {
  __shared__ int hist[256];
  int t = threadIdx.x;
  hist[t] = 0;
  __syncthreads();
  int start = blockIdx.x * EPB, end = min(E, start + EPB);
  for (int e = start + t; e < end; e += 256)
    atomicAdd(&hist[edst[e] >> 8], 1);
  __syncthreads();
  if (t < nbkt && hist[t]) atomicAdd(&bhist[t], hist[t]);
}

// scan bucket counts -> bucketbase; init global cursors
__global__ __launch_bounds__(256) void k_bscan(const int* __restrict__ bhist,
                                               int* __restrict__ gcur,
                                               int* __restrict__ bucketbase,
                                               int nbkt, int E) {
  __shared__ int sh[256];
  int t = threadIdx.x;
  int v = (t < nbkt) ? bhist[t] : 0;
  sh[t] = v;
  __syncthreads();
  for (int off = 1; off < 256; off <<= 1) {
    int x = (t >= off) ? sh[t - off] : 0;
    __syncthreads();
    sh[t] += x;
    __syncthreads();
  }
  int base = sh[t] - v;  // exclusive
  if (t < nbkt) { bucketbase[t] = base; gcur[t] = base; }
  if (t == nbkt) bucketbase[t] = E;
}

// block-local sort by bucket + bulk reservation + contiguous run writes.
// Packs (dst<<16)|src on the fly. One global atomic per (block,bucket).
__global__ __launch_bounds__(256) void k_part(const int* __restrict__ esrc,
                                              const int* __restrict__ edst,
                                              int* __restrict__ gcur,
                                              unsigned* __restrict__ ebuf,
                                              int E, int nbkt) {
  __shared__ int hist[256], lofs[256], lcur[256], gbase[256];
  __shared__ unsigned sbuf[EPB];
  int t = threadIdx.x;
  hist[t] = 0;
  __syncthreads();
  int start = blockIdx.x * EPB, end = min(E, start + EPB);
  unsigned u[8];
#pragma unroll
  for (int i = 0; i < 8; ++i) {
    int e = start + t + i * 256;
    if (e < end) {
      int s = esrc[e], d = edst[e];
      u[i] = ((unsigned)d << 16) | (unsigned)s;
      atomicAdd(&hist[d >> 8], 1);
    }
  }
  __syncthreads();
  int h = hist[t];
  lofs[t] = h;
  __syncthreads();
  for (int off = 1; off < 256; off <<= 1) {
    int x = (t >= off) ? lofs[t - off] : 0;
    __syncthreads();
    lofs[t] += x;
    __syncthreads();
  }
  lcur[t] = lofs[t] - h;                      // exclusive offset
  if (t < nbkt && h) gbase[t] = atomicAdd(&gcur[t], h);  // bulk reservation
  __syncthreads();
#pragma unroll
  for (int i = 0; i < 8; ++i) {
    int e = start + t + i * 256;
    if (e < end) {
      int b = (int)(u[i] >> 24);
      int p = atomicAdd(&lcur[b], 1);
      sbuf[p] = u[i];
    }
  }
  __syncthreads();
  int m = end - start;
  for (int i = t; i < m; i += 256) {
    unsigned v = sbuf[i];
    int b = (int)(v >> 24);
    int excl = lofs[b] - hist[b];
    ebuf[gbase[b] + (i - excl)] = v;          // contiguous per-bucket runs
  }
}

// one workgroup per bucket: local hist + scan + fill. Writes rowptr, dinv, cs(ushort).
__global__ __launch_bounds__(256) void k_local(const unsigned* __restrict__ ebuf,
                                               const int* __restrict__ bucketbase,
                                               int* __restrict__ rowptr,
                                               float* __restrict__ dinv,
                                               unsigned short* __restrict__ cs,
                                               int n) {
  __shared__ int hist[256], lofs[256], cur[256];
  int b = blockIdx.x, t = threadIdx.x;
  int rb = bucketbase[b], re = bucketbase[b + 1];
  int nbase = b << 8;
  hist[t] = 0;
  __syncthreads();
  for (int e = rb + t; e < re; e += 256) {
    int dl = (int)(ebuf[e] >> 16) - nbase;
    atomicAdd(&hist[dl], 1);
  }
  __syncthreads();
  int h = hist[t];
  lofs[t] = h;
  __syncthreads();
  for (int off = 1; off < 256; off <<= 1) {
    int x = (t >= off) ? lofs[t - off] : 0;
    __syncthreads();
    lofs[t] += x;
    __syncthreads();
  }
  int excl = lofs[t] - h;
  cur[t] = rb + excl;
  int g = nbase + t;
  if (g <= n) rowptr[g] = rb + excl;   // g==n lands here for the last bucket
  if (g < n) dinv[g] = rsqrtf((float)h + 1.0f);
  __syncthreads();
  for (int e = rb + t; e < re; e += 256) {
    unsigned u = ebuf[e];
    int dl = (int)(u >> 16) - nbase;
    int p = atomicAdd(&cur[dl], 1);
    cs[p] = (unsigned short)(u & 0xffffu);
  }
}

// ---------------- feature prep ----------------

// xs = x * dinv (bf16, padded to 16 cols)
__global__ __launch_bounds__(256) void k_pad(const float* __restrict__ x,
                                             const float* __restrict__ dinv,
                                             bf16* __restrict__ xs, int n) {
  int i = blockIdx.x * 256 + threadIdx.x;
  if (i >= n * FP) return;
  int node = i >> 4, c = i & 15;
  float v = (c < F_IN) ? x[(size_t)node * F_IN + c] * dinv[node] : 0.f;
  xs[i] = (bf16)v;
}

// WT[n][k] = bf16(W[k][n]) for both 128x128 layer weights
__global__ __launch_bounds__(256) void k_prepw2(const float* __restrict__ W2,
                                                const float* __restrict__ W3,
                                                bf16* __restrict__ WT2,
                                                bf16* __restrict__ WT3) {
  int i = blockIdx.x * 256 + threadIdx.x;  // 16384
  int nn = i >> 7, k = i & 127;
  WT2[i] = (bf16)W2[k * 128 + nn];
  WT3[i] = (bf16)W3[k * 128 + nn];
}

// ---------------- gathers ----------------

// A1[d] = dinv[d] * (xs[d] + sum xs[src])   [n][16] bf16
__global__ __launch_bounds__(256) void k_gather16(const bf16* __restrict__ xs,
                                                  const float* __restrict__ dinv,
                                                  const int* __restrict__ rowptr,
                                                  const unsigned short* __restrict__ cs,
                                                  bf16* __restrict__ A, int n) {
  int t = threadIdx.x;
  int node = blockIdx.x * 16 + (t >> 4);
  int c = t & 15;
  if (node >= n) return;
  float acc = (float)xs[(size_t)node * FP + c];
  int j = rowptr[node], jend = rowptr[node + 1];
  for (; j + 1 < jend; j += 2) {
    int s0 = cs[j], s1 = cs[j + 1];
    acc += (float)xs[(size_t)s0 * FP + c];
    acc += (float)xs[(size_t)s1 * FP + c];
  }
  if (j < jend) acc += (float)xs[(size_t)cs[j] * FP + c];
  A[(size_t)node * FP + c] = (bf16)(acc * dinv[node]);
}

// A[d] = dinv[d] * (hs[d] + sum hs[src])    [n][128] bf16; one wave per node
__global__ __launch_bounds__(256) void k_gather128(const bf16* __restrict__ hs,
                                                   const float* __restrict__ dinv,
                                                   const int* __restrict__ rowptr,
                                                   const unsigned short* __restrict__ cs,
                                                   bf16* __restrict__ A, int n) {
  int t = threadIdx.x;
  int node = blockIdx.x * 4 + (t >> 6);
  int l = t & 63;
  if (node >= n) return;
  const unsigned* h2 = (const unsigned*)hs;
  unsigned sv = h2[(size_t)node * 64 + l];
  float ax = lo16(sv), ay = hi16(sv);
  int j = rowptr[node], jend = rowptr[node + 1];
  for (; j + 3 < jend; j += 4) {
    int s0 = cs[j], s1 = cs[j + 1], s2 = cs[j + 2], s3 = cs[j + 3];
    unsigned v0 = h2[(size_t)s0 * 64 + l];
    unsigned v1 = h2[(size_t)s1 * 64 + l];
    unsigned v2 = h2[(size_t)s2 * 64 + l];
    unsigned v3 = h2[(size_t)s3 * 64 + l];
    ax += lo16(v0); ay += hi16(v0);
    ax += lo16(v1); ay += hi16(v1);
    ax += lo16(v2); ay += hi16(v2);
    ax += lo16(v3); ay += hi16(v3);
  }
  for (; j < jend; ++j) {
    unsigned v0 = h2[(size_t)cs[j] * 64 + l];
    ax += lo16(v0); ay += hi16(v0);
  }
  float dd = dinv[node];
  bf16* ap = A + (size_t)node * 128 + l * 2;
  ap[0] = (bf16)(ax * dd);
  ap[1] = (bf16)(ay * dd);
}

// ---------------- GEMMs ----------------

// A1[n,16(11 used)] @ W1[11,128] -> relu(+b)*dinv -> hs [n][128] bf16
__global__ __launch_bounds__(256) void k_gemm_in(const bf16* __restrict__ A1,
                                                 const float* __restrict__ W1,
                                                 const float* __restrict__ b1,
                                                 const float* __restrict__ dinv,
                                                 bf16* __restrict__ hs, int n) {
  __shared__ float Ws[F_IN * HID];
  int tid = threadIdx.x;
  for (int i = tid; i < F_IN * HID; i += 256) Ws[i] = W1[i];
  __syncthreads();
  int node = blockIdx.x * 16 + (tid >> 4);
  int cg = tid & 15;
  if (node >= n) return;
  float xr[F_IN];
#pragma unroll
  for (int k = 0; k < F_IN; ++k) xr[k] = (float)A1[(size_t)node * FP + k];
  float acc[8];
#pragma unroll
  for (int j = 0; j < 8; ++j) acc[j] = 0.f;
#pragma unroll
  for (int k = 0; k < F_IN; ++k) {
    const float* wr = &Ws[k * HID + cg * 8];
#pragma unroll
    for (int j = 0; j < 8; ++j) acc[j] = fmaf(xr[k], wr[j], acc[j]);
  }
  float dd = dinv[node];
  bf16* op = hs + (size_t)node * HID + cg * 8;
#pragma unroll
  for (int j = 0; j < 8; ++j)
    op[j] = (bf16)(fmaxf(acc[j] + b1[cg * 8 + j], 0.f) * dd);
}

// A[n,128](bf16) @ WT^T (bf16) -> relu(+b)*dinv -> H bf16. 64 nodes/block, MFMA 16x16x32.
__global__ __launch_bounds__(256) void k_gemm_mfma(const bf16* __restrict__ A,
                                                   const bf16* __restrict__ WT,
                                                   const float* __restrict__ b,
                                                   const float* __restrict__ dinv,
                                                   bf16* __restrict__ H, int n) {
  __shared__ bf16 Asm[64 * 128];
  __shared__ bf16 Wsm[128 * 128];
  int tid = threadIdx.x;
  int n0 = blockIdx.x * 64;
  {
    float4* As4 = (float4*)Asm;
#pragma unroll
    for (int it = 0; it < 4; ++it) {
      int i = tid + it * 256;
      int row = i >> 4, kc = i & 15;
      float4 v = make_float4(0.f, 0.f, 0.f, 0.f);
      if (n0 + row < n) v = ((const float4*)(A + (size_t)(n0 + row) * 128))[kc];
      As4[row * 16 + (kc ^ (row & 7))] = v;
    }
    const float4* Wg = (const float4*)WT;
    float4* Ws4 = (float4*)Wsm;
#pragma unroll
    for (int it = 0; it < 8; ++it) {
      int i = tid + it * 256;
      int row = i >> 4, kc = i & 15;
      Ws4[row * 16 + (kc ^ (row & 7))] = Wg[i];
    }
  }
  __syncthreads();
  int lane = tid & 63, wave = tid >> 6;
  int l15 = lane & 15, g = lane >> 4;
  f32x4 acc[8];
#pragma unroll
  for (int f = 0; f < 8; ++f) acc[f] = (f32x4){0.f, 0.f, 0.f, 0.f};
  int arow = wave * 16 + l15;
  const float4* As4 = (const float4*)Asm;
  const float4* Ws4 = (const float4*)Wsm;
#pragma unroll
  for (int kk = 0; kk < 4; ++kk) {
    int kc = kk * 4 + g;
    v8bf a = *(const v8bf*)&As4[arow * 16 + (kc ^ (arow & 7))];
#pragma unroll
    for (int f = 0; f < 8; ++f) {
      int nrow = f * 16 + l15;
      v8bf bf = *(const v8bf*)&Ws4[nrow * 16 + (kc ^ (nrow & 7))];
      acc[f] = __builtin_amdgcn_mfma_f32_16x16x32_bf16(a, bf, acc[f], 0, 0, 0);
    }
  }
  int nodebase = n0 + wave * 16 + g * 4;
  float dv[4];
#pragma unroll
  for (int j = 0; j < 4; ++j)
    dv[j] = (nodebase + j < n) ? dinv[nodebase + j] : 1.f;
#pragma unroll
  for (int f = 0; f < 8; ++f) {
    float bias = b[f * 16 + l15];
#pragma unroll
    for (int j = 0; j < 4; ++j) {
      int node = nodebase + j;
      if (node < n) {
        float v = fmaxf(acc[f][j] + bias, 0.f) * dv[j];
        H[(size_t)node * 128 + f * 16 + l15] = (bf16)v;
      }
    }
  }
}

// Layer 3: same GEMM but no H write; fused column-sum into gsum (for mean pool).
__global__ __launch_bounds__(256) void k_gemm_mfma3(const bf16* __restrict__ A,
                                                    const bf16* __restrict__ WT,
                                                    const float* __restrict__ b,
                                                    float* __restrict__ gsum, int n) {
  __shared__ bf16 Asm[64 * 128];
  __shared__ bf16 Wsm[128 * 128];
  __shared__ float colacc[128];
  int tid = threadIdx.x;
  int n0 = blockIdx.x * 64;
  if (tid < 128) colacc[tid] = 0.f;
  {
    float4* As4 = (float4*)Asm;
#pragma unroll
    for (int it = 0; it < 4; ++it) {
      int i = tid + it * 256;
      int row = i >> 4, kc = i & 15;
      float4 v = make_float4(0.f, 0.f, 0.f, 0.f);
      if (n0 + row < n) v = ((const float4*)(A + (size_t)(n0 + row) * 128))[kc];
      As4[row * 16 + (kc ^ (row & 7))] = v;
    }
    const float4* Wg = (const float4*)WT;
    float4* Ws4 = (float4*)Wsm;
#pragma unroll
    for (int it = 0; it < 8; ++it) {
      int i = tid + it * 256;
      int row = i >> 4, kc = i & 15;
      Ws4[row * 16 + (kc ^ (row & 7))] = Wg[i];
    }
  }
  __syncthreads();
  int lane = tid & 63, wave = tid >> 6;
  int l15 = lane & 15, g = lane >> 4;
  f32x4 acc[8];
#pragma unroll
  for (int f = 0; f < 8; ++f) acc[f] = (f32x4){0.f, 0.f, 0.f, 0.f};
  int arow = wave * 16 + l15;
  const float4* As4 = (const float4*)Asm;
  const float4* Ws4 = (const float4*)Wsm;
#pragma unroll
  for (int kk = 0; kk < 4; ++kk) {
    int kc = kk * 4 + g;
    v8bf a = *(const v8bf*)&As4[arow * 16 + (kc ^ (arow & 7))];
#pragma unroll
    for (int f = 0; f < 8; ++f) {
      int nrow = f * 16 + l15;
      v8bf bf = *(const v8bf*)&Ws4[nrow * 16 + (kc ^ (nrow & 7))];
      acc[f] = __builtin_amdgcn_mfma_f32_16x16x32_bf16(a, bf, acc[f], 0, 0, 0);
    }
  }
  int nodebase = n0 + wave * 16 + g * 4;
#pragma unroll
  for (int f = 0; f < 8; ++f) {
    float bias = b[f * 16 + l15];
    float sf = 0.f;
#pragma unroll
    for (int j = 0; j < 4; ++j) {
      int node = nodebase + j;
      if (node < n) sf += fmaxf(acc[f][j] + bias, 0.f);
    }
    atomicAdd(&colacc[f * 16 + l15], sf);
  }
  __syncthreads();
  if (tid < 128) atomicAdd(&gsum[tid], colacc[tid]);
}

// ---------------- head ----------------

__global__ __launch_bounds__(128) void k_head(const float* __restrict__ gsum,
    const float* __restrict__ Wv1, const float* __restrict__ bv1,
    const float* __restrict__ Wv2, const float* __restrict__ bv2,
    const float* __restrict__ Wa1, const float* __restrict__ ba1,
    const float* __restrict__ Wa2, const float* __restrict__ ba2,
    float* __restrict__ out, int n) {
  __shared__ float gs[HID], ha[HID], red[2], advs[N_ACT], vsh;
  int t = threadIdx.x;
  gs[t] = gsum[t] * (1.0f / (float)n);
  __syncthreads();
  float av = bv1[t], aa = ba1[t];
  for (int k = 0; k < HID; ++k) {
    float gk = gs[k];
    av = fmaf(gk, Wv1[k * HID + t], av);
    aa = fmaf(gk, Wa1[k * HID + t], aa);
  }
  float hv = fmaxf(av, 0.f);
  ha[t] = fmaxf(aa, 0.f);
  float pv = hv * Wv2[t];
#pragma unroll
  for (int o = 32; o > 0; o >>= 1) pv += __shfl_down(pv, o);
  if ((t & 63) == 0) red[t >> 6] = pv;
  __syncthreads();
  if (t == 0) vsh = red[0] + red[1] + bv2[0];
  if (t < N_ACT) {
    float adv = ba2[t];
    for (int j = 0; j < HID; ++j) adv = fmaf(ha[j], Wa2[j * N_ACT + t], adv);
    advs[t] = adv;
  }
  __syncthreads();
  if (t < N_ACT) {
    float m = 0.f;
#pragma unroll
    for (int a = 0; a < N_ACT; ++a) m += advs[a];
    m *= (1.0f / N_ACT);
    out[t] = vsh + advs[t] - m;
  }
}

// ---------------- launch ----------------

extern "C" void kernel_launch(void* const* d_in, const int* in_sizes, int n_in,
                              void* d_out, int out_size, void* d_ws, size_t ws_size,
                              hipStream_t stream) {
  const float* x   = (const float*)d_in[0];
  const int*   ei  = (const int*)d_in[1];
  const float* W1  = (const float*)d_in[2];
  const float* b1  = (const float*)d_in[3];
  const float* W2  = (const float*)d_in[4];
  const float* b2  = (const float*)d_in[5];
  const float* W3  = (const float*)d_in[6];
  const float* b3  = (const float*)d_in[7];
  const float* Wv1 = (const float*)d_in[8];
  const float* bv1 = (const float*)d_in[9];
  const float* Wv2 = (const float*)d_in[10];
  const float* bv2 = (const float*)d_in[11];
  const float* Wa1 = (const float*)d_in[12];
  const float* ba1 = (const float*)d_in[13];
  const float* Wa2 = (const float*)d_in[14];
  const float* ba2 = (const float*)d_in[15];
  float* out = (float*)d_out;

  const int N = in_sizes[0] / F_IN;   // 50000 (< 65536 required for u16 packing)
  const int E = in_sizes[1] / 2;      // 800000
  const int* esrc = ei;
  const int* edst = ei + E;
  const int nbkt = (N + 255) >> 8;    // 196
  const int gE = (E + EPB - 1) / EPB;

  char* p = (char*)d_ws;
  auto alloc = [&](size_t bytes) {
    void* r = (void*)p;
    p += (bytes + 1023) & ~(size_t)1023;
    return r;
  };
  unsigned* ebuf   = (unsigned*)alloc((size_t)E * 4);
  int*   bhist     = (int*)alloc((size_t)nbkt * 4);
  int*   gcur      = (int*)alloc((size_t)nbkt * 4);
  int*   bktbase   = (int*)alloc((size_t)(nbkt + 1) * 4);
  int*   rowptr    = (int*)alloc((size_t)(N + 1) * 4);
  float* dinv      = (float*)alloc((size_t)N * 4);
  unsigned short* cs = (unsigned short*)alloc((size_t)E * 2);
  bf16*  xs        = (bf16*)alloc((size_t)N * FP * 2);
  bf16*  A1        = (bf16*)alloc((size_t)N * FP * 2);
  bf16*  WT2       = (bf16*)alloc(128 * 128 * 2);
  bf16*  WT3       = (bf16*)alloc(128 * 128 * 2);
  bf16*  HB        = (bf16*)alloc((size_t)N * HID * 2);
  bf16*  AB        = (bf16*)alloc((size_t)N * HID * 2);
  float* gsum      = (float*)alloc(HID * 4);

  hipMemsetAsync(bhist, 0, (size_t)nbkt * 4, stream);
  hipMemsetAsync(gsum, 0, HID * 4, stream);

  // CSR build
  k_hist<<<gE, 256, 0, stream>>>(edst, bhist, E, nbkt);
  k_bscan<<<1, 256, 0, stream>>>(bhist, gcur, bktbase, nbkt, E);
  k_part<<<gE, 256, 0, stream>>>(esrc, edst, gcur, ebuf, E, nbkt);
  k_local<<<nbkt, 256, 0, stream>>>(ebuf, bktbase, rowptr, dinv, cs, N);

  // feature prep
  k_pad<<<(N * FP + 255) / 256, 256, 0, stream>>>(x, dinv, xs, N);
  k_prepw2<<<64, 256, 0, stream>>>(W2, W3, WT2, WT3);

  // layer 1
  k_gather16<<<(N + 15) / 16, 256, 0, stream>>>(xs, dinv, rowptr, cs, A1, N);
  k_gemm_in<<<(N + 15) / 16, 256, 0, stream>>>(A1, W1, b1, dinv, HB, N);

  // layer 2
  k_gather128<<<(N + 3) / 4, 256, 0, stream>>>(HB, dinv, rowptr, cs, AB, N);
  k_gemm_mfma<<<(N + 63) / 64, 256, 0, stream>>>(AB, WT2, b2, dinv, HB, N);

  // layer 3 (GEMM + fused column-sum; no H write)
  k_gather128<<<(N + 3) / 4, 256, 0, stream>>>(HB, dinv, rowptr, cs, AB, N);
  k_gemm_mfma3<<<(N + 63) / 64, 256, 0, stream>>>(AB, WT3, b3, gsum, N);

  // head
  k_head<<<1, 128, 0, stream>>>(gsum, Wv1, bv1, Wv2, bv2, Wa1, ba1, Wa2, ba2, out, N);
}